// Round 10
// baseline (486.582 us; speedup 1.0000x reference)
//
#include <hip/hip_runtime.h>

// ---------------------------------------------------------------------------
// GCNnet: 3x GCNConv (40->40->80->128) + global max pool + MLP(128->512->2) + softmax
// N=100000 nodes, E=1600000 edges, G=512 graphs.
// Round 18: R17's fused conv3 ran phases serially (101us = split pair; BW 1.7
// vs gather's 3.7 TB/s) because grid == one residency generation and the
// single barrier lock-steps all blocks: memory phase and compute phase never
// coexist on a CU. Fix: 4 chunks of 16 nodes, double-buffered LDS
// (aggs[2][16][84] = 10.75KB); per iteration GATHER(k+1) then GEMM(k) with
// ONE barrier -> every interval holds a memory burst + compute burst; waves
// and blocks drift -> CU-level overlap. BLK=320: chunk gather = exactly one
// slot/thread (single edge-chain latency) ~ balances the 16-node gemm.
// ---------------------------------------------------------------------------

static inline int cdiv(long a, int b) { return (int)((a + b - 1) / b); }
static inline size_t align256(size_t x) { return (x + 255) & ~(size_t)255; }

#define FXSCALE 16777216.0f           // 2^24
#define SCHUNK  1024                  // elements per scan block
#define BKT_SHIFT 6                   // 64 nodes per bucket
#define MAXNB   2048                  // LDS histogram capacity (N <= 131072)
#define TB      256                   // histogram tiles

__device__ __forceinline__ float bf2f(unsigned short u) {
    return __uint_as_float(((unsigned int)u) << 16);
}
__device__ __forceinline__ unsigned short f2bf(float f) {   // round-nearest-even
    unsigned int u = __float_as_uint(f);
    return (unsigned short)((u + 0x7FFFu + ((u >> 16) & 1u)) >> 16);
}

#define ACC4(A, U, M)                                                         \
    do {                                                                      \
        A.x += bf2f((U).x) * (M); A.y += bf2f((U).y) * (M);                   \
        A.z += bf2f((U).z) * (M); A.w += bf2f((U).w) * (M);                   \
    } while (0)

// Pass A: per-tile LDS histogram over NB buckets (bucket = col>>6).
// gHist[tile][bucket]. Fused: x f32 -> bf16 (unpadded rows, stride 40).
__global__ __launch_bounds__(512)
void histA_kernel(const int* __restrict__ col, unsigned int* __restrict__ gHist,
                  int E, int NB, int chunk,
                  const float* __restrict__ x, ushort* __restrict__ xbf, long n4) {
    __shared__ unsigned int hist[MAXNB];
    int t = blockIdx.x;
    for (int i = threadIdx.x; i < NB; i += 512) hist[i] = 0u;
    __syncthreads();
    int s = t * chunk, e = min(s + chunk, E);
    for (int i = s + threadIdx.x; i < e; i += 512)
        atomicAdd(&hist[(unsigned int)col[i] >> BKT_SHIFT], 1u);
    // fused f2bf: i/10 = row, i%10 = float4 slot -> xbf[row*40 + slot*4]
    long gid = (long)t * 512 + threadIdx.x, gstride = (long)TB * 512;
    for (long i = gid; i < n4; i += gstride) {
        float4 v = ((const float4*)x)[i];
        long r = i / 10, c = i % 10;
        *(ushort4*)(xbf + r * 40 + c * 4) =
            make_ushort4(f2bf(v.x), f2bf(v.y), f2bf(v.z), f2bf(v.w));
    }
    __syncthreads();
    for (int b = threadIdx.x; b < NB; b += 512)
        gHist[(size_t)t * NB + b] = hist[b];
}

// scan phase A (histogram variant): per-block sums of the bucket-major view
// element i -> gHist[(i&255)*NB + (i>>8)]   (i = bucket*256 + tile)
__global__ void scanAH_kernel(const unsigned int* __restrict__ gHist,
                              int* __restrict__ blockSums, int TOT, int NB) {
    __shared__ int wred[4];
    int tid = threadIdx.x, lane = tid & 63, wid = tid >> 6;
    int i0 = blockIdx.x * SCHUNK + tid * 4;
    int s = 0;
#pragma unroll
    for (int k = 0; k < 4; ++k) {
        int i = i0 + k;
        if (i < TOT) s += (int)gHist[(size_t)(i & 255) * NB + (i >> 8)];
    }
#pragma unroll
    for (int off = 32; off > 0; off >>= 1) s += __shfl_down(s, off, 64);
    if (lane == 0) wred[wid] = s;
    __syncthreads();
    if (tid == 0) blockSums[blockIdx.x] = wred[0] + wred[1] + wred[2] + wred[3];
}

// scan phase B: one block, exclusive scan of blockSums[nb] (nb <= 1024);
// writes grand total into offs[N] (= E).
__global__ void scanB_kernel(int* __restrict__ blockSums, int* __restrict__ offs,
                             int nb, int N) {
    __shared__ int wsum[16];
    int tid = threadIdx.x, lane = tid & 63, wid = tid >> 6;
    int v = (tid < nb) ? blockSums[tid] : 0;
    int incl = v;
#pragma unroll
    for (int off = 1; off < 64; off <<= 1) {
        int t = __shfl_up(incl, off, 64);
        if (lane >= off) incl += t;
    }
    if (lane == 63) wsum[wid] = incl;
    __syncthreads();
    if (wid == 0 && lane < 16) {
        int w = wsum[lane];
        int ic = w;
#pragma unroll
        for (int off = 1; off < 16; off <<= 1) {
            int t = __shfl_up(ic, off, 64);
            if (lane >= off) ic += t;
        }
        wsum[lane] = ic - w;   // exclusive
    }
    __syncthreads();
    if (tid < nb) blockSums[tid] = wsum[wid] + incl - v;   // exclusive prefix
    if (tid == 1023) offs[N] = wsum[15] + incl;            // grand total
}

// scan phase C (histogram variant): local exclusive scan + block offset ->
// scanned[i] = global output cursor for (bucket = i>>8, tile = i&255)
__global__ void scanCH_kernel(const unsigned int* __restrict__ gHist,
                              const int* __restrict__ blockSums,
                              unsigned int* __restrict__ scanned, int TOT, int NB) {
    __shared__ int wsum[4];
    int tid = threadIdx.x, lane = tid & 63, wid = tid >> 6;
    int i0 = blockIdx.x * SCHUNK + tid * 4;
    int v0 = 0, v1 = 0, v2 = 0, v3 = 0;
    if (i0 + 0 < TOT) v0 = (int)gHist[(size_t)((i0 + 0) & 255) * NB + ((i0 + 0) >> 8)];
    if (i0 + 1 < TOT) v1 = (int)gHist[(size_t)((i0 + 1) & 255) * NB + ((i0 + 1) >> 8)];
    if (i0 + 2 < TOT) v2 = (int)gHist[(size_t)((i0 + 2) & 255) * NB + ((i0 + 2) >> 8)];
    if (i0 + 3 < TOT) v3 = (int)gHist[(size_t)((i0 + 3) & 255) * NB + ((i0 + 3) >> 8)];
    int sum = v0 + v1 + v2 + v3;
    int incl = sum;
#pragma unroll
    for (int off = 1; off < 64; off <<= 1) {
        int t = __shfl_up(incl, off, 64);
        if (lane >= off) incl += t;
    }
    if (lane == 63) wsum[wid] = incl;
    __syncthreads();
    if (tid == 0) {
        int c = 0;
#pragma unroll
        for (int k = 0; k < 4; ++k) { int t = wsum[k]; wsum[k] = c; c += t; }
    }
    __syncthreads();
    int pre = blockSums[blockIdx.x] + wsum[wid] + (incl - sum);
    if (i0 + 0 < TOT) scanned[i0 + 0] = (unsigned int)pre;
    if (i0 + 1 < TOT) scanned[i0 + 1] = (unsigned int)(pre + v0);
    if (i0 + 2 < TOT) scanned[i0 + 2] = (unsigned int)(pre + v0 + v1);
    if (i0 + 3 < TOT) scanned[i0 + 3] = (unsigned int)(pre + v0 + v1 + v2);
}

// Pass C: scatter edges into bucket-grouped semi[] via LDS cursors.
// semi[pos] = {row | (col&63)<<17, wbits} (int2, row < 2^17).
__global__ __launch_bounds__(512)
void scatterC_kernel(const int* __restrict__ row, const int* __restrict__ col,
                     const float* __restrict__ w,
                     const unsigned int* __restrict__ scanned,
                     int2* __restrict__ semi, int E, int NB, int chunk) {
    __shared__ unsigned int cur[MAXNB];
    int t = blockIdx.x;
    for (int b = threadIdx.x; b < NB; b += 512)
        cur[b] = scanned[(size_t)b * TB + t];
    __syncthreads();
    int s = t * chunk, e = min(s + chunk, E);
    for (int i = s + threadIdx.x; i < e; i += 512) {
        int c = col[i];
        unsigned int pos = atomicAdd(&cur[(unsigned int)c >> BKT_SHIFT], 1u);
        semi[pos] = make_int2(row[i] | ((c & 63) << 17), __float_as_int(w[i]));
    }
}

// Pass D: one block per bucket (64 nodes). Fine counting sort by c6,
// per-node weighted degree (fixed-point LDS atomics) -> perm {row,wbits},
// offs, dinv. All atomics LDS.
__global__ __launch_bounds__(256)
void fineD_kernel(const int2* __restrict__ semi, const unsigned int* __restrict__ scanned,
                  int* __restrict__ offs, float* __restrict__ dinv,
                  int2* __restrict__ perm, int E, int N, int NB) {
    __shared__ unsigned int cnt[64], cur[64], wsum[64];
    __shared__ int nodeOffs[64];
    int b = blockIdx.x, tid = threadIdx.x;
    int s = (int)scanned[(size_t)b * TB];
    int e = (b + 1 < NB) ? (int)scanned[(size_t)(b + 1) * TB] : E;
    if (tid < 64) { cnt[tid] = 0u; wsum[tid] = 0u; }
    __syncthreads();
    for (int i = s + tid; i < e; i += 256) {
        int2 v = semi[i];
        int c6 = (v.x >> 17) & 63;
        atomicAdd(&cnt[c6], 1u);
        atomicAdd(&wsum[c6], (unsigned int)llrintf(__int_as_float(v.y) * FXSCALE));
    }
    __syncthreads();
    if (tid < 64) {
        int v = (int)cnt[tid];
        int incl = v;
#pragma unroll
        for (int off = 1; off < 64; off <<= 1) {
            int u = __shfl_up(incl, off, 64);
            if (tid >= off) incl += u;
        }
        nodeOffs[tid] = incl - v;          // exclusive within bucket
        cur[tid] = (unsigned int)(incl - v);
    }
    __syncthreads();
    for (int i = s + tid; i < e; i += 256) {
        int2 v = semi[i];
        int c6 = (v.x >> 17) & 63;
        unsigned int r = atomicAdd(&cur[c6], 1u);
        perm[s + (int)r] = make_int2(v.x & 0x1FFFF, v.y);   // {row, wbits}
    }
    if (tid < 64) {
        int node = (b << BKT_SHIFT) + tid;
        if (node < N) {
            offs[node] = s + nodeOffs[tid];
            float deg = (float)wsum[tid] * (1.0f / FXSCALE);
            dinv[node] = rsqrtf(deg + 1.0f);
        }
    }
    if (b == NB - 1 && tid == 0) offs[N] = E;
}

// Pass E: perm.y = dinv[row] * w * dinv[col]  (thread per destination node)
__global__ void normE_kernel(const int* __restrict__ offs, const float* __restrict__ dinv,
                             int2* __restrict__ perm, int N) {
    int n = blockIdx.x * blockDim.x + threadIdx.x;
    if (n >= N) return;
    int s = offs[n], e = offs[n + 1];
    float dc = dinv[n];
    for (int j = s; j < e; ++j) {
        int2 p = perm[j];
        float nm = dinv[p.x] * __int_as_float(p.y) * dc;
        perm[j] = make_int2(p.x, __float_as_int(nm));
    }
}

// Fused conv (conv1/conv2): phase1 = R11 gather into LDS agg (rows padded to
// K+4 floats vs phase-2 bank conflicts); sync; phase2 = gemm from LDS, relu,
// bf16 out. Removes the bufA global round-trip entirely.
template<int K, int FOUT, int NPB, int BLK>
__global__ __launch_bounds__(BLK)
void fused_conv_kernel(const int* __restrict__ offs, const int2* __restrict__ perm,
                       const ushort* __restrict__ H, const float* __restrict__ dinv,
                       const float* __restrict__ W, const float* __restrict__ bias,
                       ushort* __restrict__ out, int N) {
    constexpr int TPN = K / 4;
    constexpr int TPQ = FOUT / 4;
    constexpr int NPT = 4;
    constexpr int KP = K + 4;              // padded agg row (floats)
    static_assert((NPB * TPN) % BLK == 0, "phase1 tiling");
    static_assert((NPB / NPT) * TPQ == BLK, "phase2 tiling");
    __shared__ float wsm[K * FOUT];
    __shared__ float aggs[NPB * KP];
    for (int i = threadIdx.x; i < K * FOUT; i += BLK) wsm[i] = W[i];

    // ---- phase 1: gather into LDS ----
#pragma unroll
    for (int p0 = 0; p0 < NPB * TPN; p0 += BLK) {
        int p = p0 + threadIdx.x;
        int nl = p / TPN, q = p % TPN;
        int node = blockIdx.x * NPB + nl;
        float4 a0 = make_float4(0.f, 0.f, 0.f, 0.f);
        float4 a1 = make_float4(0.f, 0.f, 0.f, 0.f);
        if (node < N) {
            int s = offs[node], e = offs[node + 1];
            int j = s;
            for (; j + 4 <= e; j += 4) {
                int2 p0e = perm[j + 0], p1e = perm[j + 1];
                int2 p2e = perm[j + 2], p3e = perm[j + 3];
                ushort4 u0 = *(const ushort4*)(H + (long)p0e.x * K + q * 4);
                ushort4 u1 = *(const ushort4*)(H + (long)p1e.x * K + q * 4);
                ushort4 u2 = *(const ushort4*)(H + (long)p2e.x * K + q * 4);
                ushort4 u3 = *(const ushort4*)(H + (long)p3e.x * K + q * 4);
                ACC4(a0, u0, __int_as_float(p0e.y));
                ACC4(a1, u1, __int_as_float(p1e.y));
                ACC4(a0, u2, __int_as_float(p2e.y));
                ACC4(a1, u3, __int_as_float(p3e.y));
            }
            for (; j < e; ++j) {
                int2 pe = perm[j];
                ushort4 u = *(const ushort4*)(H + (long)pe.x * K + q * 4);
                ACC4(a0, u, __int_as_float(pe.y));
            }
            float di = dinv[node], d2 = di * di;
            ushort4 su = *(const ushort4*)(H + (long)node * K + q * 4);
            ACC4(a0, su, d2);
        }
        a0.x += a1.x; a0.y += a1.y; a0.z += a1.z; a0.w += a1.w;
        *(float4*)&aggs[nl * KP + q * 4] = a0;
    }
    __syncthreads();

    // ---- phase 2: gemm from LDS ----
    int q = threadIdx.x % TPQ, pg = threadIdx.x / TPQ;
    long nbase = (long)blockIdx.x * NPB + (long)pg * NPT;
    float4 acc[NPT];
#pragma unroll
    for (int t = 0; t < NPT; ++t) acc[t] = make_float4(0.f, 0.f, 0.f, 0.f);
    const float* wq = wsm + q * 4;
#pragma unroll 4
    for (int i = 0; i < K / 4; ++i) {
        float4 xv[NPT];
#pragma unroll
        for (int t = 0; t < NPT; ++t)
            xv[t] = *(const float4*)&aggs[(pg * NPT + t) * KP + i * 4];
#pragma unroll
        for (int j = 0; j < 4; ++j) {
            float4 wv = *(const float4*)(wq + (i * 4 + j) * FOUT);
#pragma unroll
            for (int t = 0; t < NPT; ++t) {
                float v = ((const float*)&xv[t])[j];
                acc[t].x += v * wv.x; acc[t].y += v * wv.y;
                acc[t].z += v * wv.z; acc[t].w += v * wv.w;
            }
        }
    }
    float4 bv = *(const float4*)(bias + q * 4);
#pragma unroll
    for (int t = 0; t < NPT; ++t) {
        long n = nbase + t;
        if (n < N) {
            float ox = fmaxf(acc[t].x + bv.x, 0.f);
            float oy = fmaxf(acc[t].y + bv.y, 0.f);
            float oz = fmaxf(acc[t].z + bv.z, 0.f);
            float ow = fmaxf(acc[t].w + bv.w, 0.f);
            *(ushort4*)(out + n * FOUT + q * 4) =
                make_ushort4(f2bf(ox), f2bf(oy), f2bf(oz), f2bf(ow));
        }
    }
}

// Fused conv3 + pool v2: 4 chunks of CH=16 nodes, double-buffered LDS agg
// (aggs[2][16][84] = 10.75KB). Iteration k: GATHER(k+1) (memory, first) then
// GEMM(k) (compute), ONE barrier -> each barrier interval holds a memory
// burst + a compute burst; waves/blocks drift -> CU-level overlap.
// W3 read from global (L1/L2-hot). BLK=320: gather chunk = 1 slot/thread.
template<int K, int FOUT, int BLK>   // 80, 128, 320
__global__ __launch_bounds__(BLK)
void fused_conv3_pool_kernel(const int* __restrict__ offs, const int2* __restrict__ perm,
                             const ushort* __restrict__ H, const float* __restrict__ dinv,
                             const float* __restrict__ W, const float* __restrict__ bias,
                             const int* __restrict__ batch,
                             unsigned int* __restrict__ g, int N) {
    constexpr int TPN = K / 4;            // 20 slots per node
    constexpr int CH  = BLK / TPN;        // 16 nodes per chunk
    constexpr int NPB = 4 * CH;           // 64 nodes per block
    constexpr int KP  = K + 4;            // 84
    static_assert(BLK % TPN == 0, "chunk tiling");
    __shared__ float aggs[2][CH * KP];
    __shared__ unsigned int gma[2 * FOUT];
    __shared__ int gfirst;

    int bb = blockIdx.x * NPB;
    if (threadIdx.x == 0) gfirst = batch[min(bb, N - 1)];
    for (int i = threadIdx.x; i < 2 * FOUT; i += BLK) gma[i] = 0u;

    int gnl = threadIdx.x / TPN;          // gather: node-in-chunk
    int gq  = threadIdx.x % TPN;          // gather: feature slot
    int mpg = threadIdx.x >> 5;           // gemm: node-pair id (use < CH/2)
    int mq  = threadIdx.x & 31;           // gemm: output quad

    // ---- gather chunk c into buffer b (one slot per thread) ----
    auto GATHER = [&](int c, int b) {
        int node = bb + c * CH + gnl;
        float4 a0 = make_float4(0.f, 0.f, 0.f, 0.f);
        float4 a1 = make_float4(0.f, 0.f, 0.f, 0.f);
        if (node < N) {
            int s = offs[node], e = offs[node + 1];
            int j = s;
            for (; j + 4 <= e; j += 4) {
                int2 p0e = perm[j + 0], p1e = perm[j + 1];
                int2 p2e = perm[j + 2], p3e = perm[j + 3];
                ushort4 u0 = *(const ushort4*)(H + (long)p0e.x * K + gq * 4);
                ushort4 u1 = *(const ushort4*)(H + (long)p1e.x * K + gq * 4);
                ushort4 u2 = *(const ushort4*)(H + (long)p2e.x * K + gq * 4);
                ushort4 u3 = *(const ushort4*)(H + (long)p3e.x * K + gq * 4);
                ACC4(a0, u0, __int_as_float(p0e.y));
                ACC4(a1, u1, __int_as_float(p1e.y));
                ACC4(a0, u2, __int_as_float(p2e.y));
                ACC4(a1, u3, __int_as_float(p3e.y));
            }
            for (; j < e; ++j) {
                int2 pe = perm[j];
                ushort4 u = *(const ushort4*)(H + (long)pe.x * K + gq * 4);
                ACC4(a0, u, __int_as_float(pe.y));
            }
            float di = dinv[node], d2 = di * di;
            ushort4 su = *(const ushort4*)(H + (long)node * K + gq * 4);
            ACC4(a0, su, d2);
        }
        a0.x += a1.x; a0.y += a1.y; a0.z += a1.z; a0.w += a1.w;
        *(float4*)&aggs[b][gnl * KP + gq * 4] = a0;   // zeros if node >= N
    };

    // ---- gemm chunk c from buffer b: 2 nodes/thread, 256 active ----
    auto GEMM = [&](int c, int b) {
        if (mpg < CH / 2) {
            int n0 = bb + c * CH + mpg * 2;
            float4 A0 = make_float4(0.f, 0.f, 0.f, 0.f);
            float4 A1 = make_float4(0.f, 0.f, 0.f, 0.f);
            const float* wq = W + mq * 4;
#pragma unroll 4
            for (int i = 0; i < TPN; ++i) {
                float4 x0 = *(const float4*)&aggs[b][(mpg * 2 + 0) * KP + i * 4];
                float4 x1 = *(const float4*)&aggs[b][(mpg * 2 + 1) * KP + i * 4];
#pragma unroll
                for (int j = 0; j < 4; ++j) {
                    float4 wv = *(const float4*)(wq + (i * 4 + j) * FOUT);
                    float v0 = ((const float*)&x0)[j];
                    float v1 = ((const float*)&x1)[j];
                    A0.x += v0 * wv.x; A0.y += v0 * wv.y;
                    A0.z += v0 * wv.z; A0.w += v0 * wv.w;
                    A1.x += v1 * wv.x; A1.y += v1 * wv.y;
                    A1.z += v1 * wv.z; A1.w += v1 * wv.w;
                }
            }
            float4 bv = *(const float4*)(bias + mq * 4);
#pragma unroll
            for (int t = 0; t < 2; ++t) {
                long n = n0 + t;
                float4 A = t ? A1 : A0;
                if (n < N) {
                    unsigned int bx = __float_as_uint(fmaxf(A.x + bv.x, 0.f));
                    unsigned int by = __float_as_uint(fmaxf(A.y + bv.y, 0.f));
                    unsigned int bz = __float_as_uint(fmaxf(A.z + bv.z, 0.f));
                    unsigned int bw = __float_as_uint(fmaxf(A.w + bv.w, 0.f));
                    int rel = batch[n] - gfirst;
                    if (rel < 2) {
                        unsigned int* d = gma + rel * FOUT + mq * 4;
                        atomicMax(d + 0, bx); atomicMax(d + 1, by);
                        atomicMax(d + 2, bz); atomicMax(d + 3, bw);
                    } else {
                        unsigned int* d = g + (long)batch[n] * FOUT + mq * 4;
                        atomicMax(d + 0, bx); atomicMax(d + 1, by);
                        atomicMax(d + 2, bz); atomicMax(d + 3, bw);
                    }
                }
            }
        }
    };

    // ---- pipelined main loop ----
    GATHER(0, 0);
    __syncthreads();
#pragma unroll
    for (int k = 0; k < 4; ++k) {
        if (k < 3) GATHER(k + 1, (k + 1) & 1);   // memory burst (issued first)
        GEMM(k, k & 1);                          // compute burst
        __syncthreads();                         // orders G(k+1) vs M(k+1), M(k) vs G(k+2)
    }
    // flush 2-graph LDS pool window
    for (int i = threadIdx.x; i < 2 * FOUT; i += BLK) {
        unsigned int v = gma[i];
        if (v) atomicMax(&g[(long)(gfirst + i / FOUT) * FOUT + (i % FOUT)], v);
    }
}

// one block per graph: relu(g@Wfc1+bfc1) @ Wfc2 + bfc2 -> softmax
__global__ void fc_kernel(const float* __restrict__ g, const float* __restrict__ Wfc1,
                          const float* __restrict__ bfc1, const float* __restrict__ Wfc2,
                          const float* __restrict__ bfc2, float* __restrict__ out) {
    __shared__ float gs[128];
    __shared__ float red0[256], red1[256];
    int b = blockIdx.x, tid = threadIdx.x;
    if (tid < 128) gs[tid] = g[b * 128 + tid];
    __syncthreads();
    float h0 = bfc1[tid], h1 = bfc1[tid + 256];
    for (int k = 0; k < 128; ++k) {
        float gv = gs[k];
        h0 += gv * Wfc1[k * 512 + tid];
        h1 += gv * Wfc1[k * 512 + tid + 256];
    }
    h0 = fmaxf(h0, 0.f); h1 = fmaxf(h1, 0.f);
    red0[tid] = h0 * Wfc2[tid * 2 + 0] + h1 * Wfc2[(tid + 256) * 2 + 0];
    red1[tid] = h0 * Wfc2[tid * 2 + 1] + h1 * Wfc2[(tid + 256) * 2 + 1];
    __syncthreads();
    for (int s = 128; s > 0; s >>= 1) {
        if (tid < s) { red0[tid] += red0[tid + s]; red1[tid] += red1[tid + s]; }
        __syncthreads();
    }
    if (tid == 0) {
        float L0 = red0[0] + bfc2[0], L1 = red1[0] + bfc2[1];
        float m = fmaxf(L0, L1);
        float e0 = expf(L0 - m), e1 = expf(L1 - m);
        float inv = 1.f / (e0 + e1);
        out[b * 2 + 0] = e0 * inv;
        out[b * 2 + 1] = e1 * inv;
    }
}

extern "C" void kernel_launch(void* const* d_in, const int* in_sizes, int n_in,
                              void* d_out, int out_size, void* d_ws, size_t ws_size,
                              hipStream_t stream) {
    const float* x     = (const float*)d_in[0];
    const int*   ei    = (const int*)d_in[1];
    const float* ew    = (const float*)d_in[2];
    const int*   batch = (const int*)d_in[3];
    const float* W1    = (const float*)d_in[4];
    const float* b1    = (const float*)d_in[5];
    const float* W2    = (const float*)d_in[6];
    const float* b2    = (const float*)d_in[7];
    const float* W3    = (const float*)d_in[8];
    const float* b3    = (const float*)d_in[9];
    const float* Wfc1  = (const float*)d_in[10];
    const float* bfc1  = (const float*)d_in[11];
    const float* Wfc2  = (const float*)d_in[12];
    const float* bfc2  = (const float*)d_in[13];

    const int N = in_sizes[3];      // 100000
    const int E = in_sizes[2];      // 1600000
    const int* row = ei;
    const int* col = ei + E;

    char* ws = (char*)d_ws;
    float* dinv   = (float*)ws;              ws += align256((size_t)N * 4);
    int*   offs   = (int*)ws;                ws += align256((size_t)(N + 1) * 4);
    int*   bsums  = (int*)ws;                ws += align256((size_t)1024 * 4);
    int2*  perm   = (int2*)ws;               ws += align256((size_t)E * 8);
    float* bufA   = (float*)ws;              ws += align256((size_t)N * 128 * 4);  // build transients
    ushort* bufH1 = (ushort*)ws;             ws += align256((size_t)N * 40 * 2);   // H1 bf16
    ushort* bufH2 = (ushort*)ws;             ws += align256((size_t)N * 80 * 2);   // H2 bf16
    ushort* xbf   = (ushort*)ws;             ws += align256((size_t)N * 40 * 2);   // x bf16
    float* g      = (float*)ws;              ws += align256((size_t)512 * 128 * 4);

    const int NB   = cdiv(N, 64);            // 1563 buckets (<= MAXNB)
    const int TOT  = NB * TB;                // (bucket, tile) cells = 400128
    const int chunkE = cdiv(E, TB);          // edges per tile = 6250
    const int nScanH = cdiv(TOT, SCHUNK);    // 391 (<= 1024)

    // transients aliased into bufA (51.2MB; all dead before convs):
    // semi int2 (12.8MB) | gHist u32[TOT] (1.6MB) | scanned u32[TOT] (1.6MB)
    int2* semi = (int2*)bufA;
    unsigned int* gHist =
        (unsigned int*)((char*)bufA + align256((size_t)E * 8));
    unsigned int* scanned =
        (unsigned int*)((char*)gHist + align256((size_t)TOT * 4));

    const int B = 256;

    // --- atomic-free CSR build ---
    histA_kernel<<<TB, 512, 0, stream>>>(col, gHist, E, NB, chunkE,
                                         x, xbf, (long)N * 10);
    scanAH_kernel<<<nScanH, B, 0, stream>>>(gHist, bsums, TOT, NB);
    scanB_kernel<<<1, 1024, 0, stream>>>(bsums, offs, nScanH, N);
    scanCH_kernel<<<nScanH, B, 0, stream>>>(gHist, bsums, scanned, TOT, NB);
    scatterC_kernel<<<TB, 512, 0, stream>>>(row, col, ew, scanned, semi, E, NB, chunkE);
    fineD_kernel<<<NB, 256, 0, stream>>>(semi, scanned, offs, dinv, perm, E, N, NB);
    normE_kernel<<<cdiv(N, B), B, 0, stream>>>(offs, dinv, perm, N);

    // --- conv1 fused: H1 = relu((A*x)@W1 + b1) -> bufH1 (bf16) ---
    fused_conv_kernel<40, 40, 128, 320><<<cdiv(N, 128), 320, 0, stream>>>(
        offs, perm, xbf, dinv, W1, b1, bufH1, N);

    // --- conv2 fused: H2 = relu((A*H1)@W2 + b2) -> bufH2 (bf16) ---
    fused_conv_kernel<40, 80, 64, 320><<<cdiv(N, 64), 320, 0, stream>>>(
        offs, perm, bufH1, dinv, W2, b2, bufH2, N);

    // --- conv3 fused v2 (pipelined chunks): pool(relu((A*H2)@W3 + b3)) -> g ---
    hipMemsetAsync(g, 0, (size_t)512 * 128 * 4, stream);
    fused_conv3_pool_kernel<80, 128, 320><<<cdiv(N, 64), 320, 0, stream>>>(
        offs, perm, bufH2, dinv, W3, b3, batch, (unsigned int*)g, N);

    // --- MLP + softmax ---
    fc_kernel<<<512, 256, 0, stream>>>(g, Wfc1, bfc1, Wfc2, bfc2, (float*)d_out);
}

// Round 11
// 367.518 us; speedup vs baseline: 1.3240x; 1.3240x over previous
//
#include <hip/hip_runtime.h>

// ---------------------------------------------------------------------------
// GCNnet: 3x GCNConv (40->40->80->128) + global max pool + MLP(128->512->2) + softmax
// N=100000 nodes, E=1600000 edges, G=512 graphs.
// Round 19: R18's chunked-barrier pipeline regressed 2.3x (straggler-amplified
// barriers + residency collapse) -> reverted to R17's two-phase conv3 body.
// R17's lock-step diagnosis stands; new lever = MORE, SMALLER, INDEPENDENT
// blocks: NPB=32, BLK=128 (phase1 = 5 rounds, phase2 = 4 pg x NPT=8, same
// per-thread code as R17). LDS 23->12KB -> ~13 blocks/CU, independent
// barriers drift -> each CU holds a mix of phase-1 (memory) and phase-2
// (FMA) blocks = grid-level overlap. Worst case == R17, not R18.
// ---------------------------------------------------------------------------

static inline int cdiv(long a, int b) { return (int)((a + b - 1) / b); }
static inline size_t align256(size_t x) { return (x + 255) & ~(size_t)255; }

#define FXSCALE 16777216.0f           // 2^24
#define SCHUNK  1024                  // elements per scan block
#define BKT_SHIFT 6                   // 64 nodes per bucket
#define MAXNB   2048                  // LDS histogram capacity (N <= 131072)
#define TB      256                   // histogram tiles

__device__ __forceinline__ float bf2f(unsigned short u) {
    return __uint_as_float(((unsigned int)u) << 16);
}
__device__ __forceinline__ unsigned short f2bf(float f) {   // round-nearest-even
    unsigned int u = __float_as_uint(f);
    return (unsigned short)((u + 0x7FFFu + ((u >> 16) & 1u)) >> 16);
}

#define ACC4(A, U, M)                                                         \
    do {                                                                      \
        A.x += bf2f((U).x) * (M); A.y += bf2f((U).y) * (M);                   \
        A.z += bf2f((U).z) * (M); A.w += bf2f((U).w) * (M);                   \
    } while (0)

// Pass A: per-tile LDS histogram over NB buckets (bucket = col>>6).
// gHist[tile][bucket]. Fused: x f32 -> bf16 (unpadded rows, stride 40).
__global__ __launch_bounds__(512)
void histA_kernel(const int* __restrict__ col, unsigned int* __restrict__ gHist,
                  int E, int NB, int chunk,
                  const float* __restrict__ x, ushort* __restrict__ xbf, long n4) {
    __shared__ unsigned int hist[MAXNB];
    int t = blockIdx.x;
    for (int i = threadIdx.x; i < NB; i += 512) hist[i] = 0u;
    __syncthreads();
    int s = t * chunk, e = min(s + chunk, E);
    for (int i = s + threadIdx.x; i < e; i += 512)
        atomicAdd(&hist[(unsigned int)col[i] >> BKT_SHIFT], 1u);
    // fused f2bf: i/10 = row, i%10 = float4 slot -> xbf[row*40 + slot*4]
    long gid = (long)t * 512 + threadIdx.x, gstride = (long)TB * 512;
    for (long i = gid; i < n4; i += gstride) {
        float4 v = ((const float4*)x)[i];
        long r = i / 10, c = i % 10;
        *(ushort4*)(xbf + r * 40 + c * 4) =
            make_ushort4(f2bf(v.x), f2bf(v.y), f2bf(v.z), f2bf(v.w));
    }
    __syncthreads();
    for (int b = threadIdx.x; b < NB; b += 512)
        gHist[(size_t)t * NB + b] = hist[b];
}

// scan phase A (histogram variant): per-block sums of the bucket-major view
// element i -> gHist[(i&255)*NB + (i>>8)]   (i = bucket*256 + tile)
__global__ void scanAH_kernel(const unsigned int* __restrict__ gHist,
                              int* __restrict__ blockSums, int TOT, int NB) {
    __shared__ int wred[4];
    int tid = threadIdx.x, lane = tid & 63, wid = tid >> 6;
    int i0 = blockIdx.x * SCHUNK + tid * 4;
    int s = 0;
#pragma unroll
    for (int k = 0; k < 4; ++k) {
        int i = i0 + k;
        if (i < TOT) s += (int)gHist[(size_t)(i & 255) * NB + (i >> 8)];
    }
#pragma unroll
    for (int off = 32; off > 0; off >>= 1) s += __shfl_down(s, off, 64);
    if (lane == 0) wred[wid] = s;
    __syncthreads();
    if (tid == 0) blockSums[blockIdx.x] = wred[0] + wred[1] + wred[2] + wred[3];
}

// scan phase B: one block, exclusive scan of blockSums[nb] (nb <= 1024);
// writes grand total into offs[N] (= E).
__global__ void scanB_kernel(int* __restrict__ blockSums, int* __restrict__ offs,
                             int nb, int N) {
    __shared__ int wsum[16];
    int tid = threadIdx.x, lane = tid & 63, wid = tid >> 6;
    int v = (tid < nb) ? blockSums[tid] : 0;
    int incl = v;
#pragma unroll
    for (int off = 1; off < 64; off <<= 1) {
        int t = __shfl_up(incl, off, 64);
        if (lane >= off) incl += t;
    }
    if (lane == 63) wsum[wid] = incl;
    __syncthreads();
    if (wid == 0 && lane < 16) {
        int w = wsum[lane];
        int ic = w;
#pragma unroll
        for (int off = 1; off < 16; off <<= 1) {
            int t = __shfl_up(ic, off, 64);
            if (lane >= off) ic += t;
        }
        wsum[lane] = ic - w;   // exclusive
    }
    __syncthreads();
    if (tid < nb) blockSums[tid] = wsum[wid] + incl - v;   // exclusive prefix
    if (tid == 1023) offs[N] = wsum[15] + incl;            // grand total
}

// scan phase C (histogram variant): local exclusive scan + block offset ->
// scanned[i] = global output cursor for (bucket = i>>8, tile = i&255)
__global__ void scanCH_kernel(const unsigned int* __restrict__ gHist,
                              const int* __restrict__ blockSums,
                              unsigned int* __restrict__ scanned, int TOT, int NB) {
    __shared__ int wsum[4];
    int tid = threadIdx.x, lane = tid & 63, wid = tid >> 6;
    int i0 = blockIdx.x * SCHUNK + tid * 4;
    int v0 = 0, v1 = 0, v2 = 0, v3 = 0;
    if (i0 + 0 < TOT) v0 = (int)gHist[(size_t)((i0 + 0) & 255) * NB + ((i0 + 0) >> 8)];
    if (i0 + 1 < TOT) v1 = (int)gHist[(size_t)((i0 + 1) & 255) * NB + ((i0 + 1) >> 8)];
    if (i0 + 2 < TOT) v2 = (int)gHist[(size_t)((i0 + 2) & 255) * NB + ((i0 + 2) >> 8)];
    if (i0 + 3 < TOT) v3 = (int)gHist[(size_t)((i0 + 3) & 255) * NB + ((i0 + 3) >> 8)];
    int sum = v0 + v1 + v2 + v3;
    int incl = sum;
#pragma unroll
    for (int off = 1; off < 64; off <<= 1) {
        int t = __shfl_up(incl, off, 64);
        if (lane >= off) incl += t;
    }
    if (lane == 63) wsum[wid] = incl;
    __syncthreads();
    if (tid == 0) {
        int c = 0;
#pragma unroll
        for (int k = 0; k < 4; ++k) { int t = wsum[k]; wsum[k] = c; c += t; }
    }
    __syncthreads();
    int pre = blockSums[blockIdx.x] + wsum[wid] + (incl - sum);
    if (i0 + 0 < TOT) scanned[i0 + 0] = (unsigned int)pre;
    if (i0 + 1 < TOT) scanned[i0 + 1] = (unsigned int)(pre + v0);
    if (i0 + 2 < TOT) scanned[i0 + 2] = (unsigned int)(pre + v0 + v1);
    if (i0 + 3 < TOT) scanned[i0 + 3] = (unsigned int)(pre + v0 + v1 + v2);
}

// Pass C: scatter edges into bucket-grouped semi[] via LDS cursors.
// semi[pos] = {row | (col&63)<<17, wbits} (int2, row < 2^17).
__global__ __launch_bounds__(512)
void scatterC_kernel(const int* __restrict__ row, const int* __restrict__ col,
                     const float* __restrict__ w,
                     const unsigned int* __restrict__ scanned,
                     int2* __restrict__ semi, int E, int NB, int chunk) {
    __shared__ unsigned int cur[MAXNB];
    int t = blockIdx.x;
    for (int b = threadIdx.x; b < NB; b += 512)
        cur[b] = scanned[(size_t)b * TB + t];
    __syncthreads();
    int s = t * chunk, e = min(s + chunk, E);
    for (int i = s + threadIdx.x; i < e; i += 512) {
        int c = col[i];
        unsigned int pos = atomicAdd(&cur[(unsigned int)c >> BKT_SHIFT], 1u);
        semi[pos] = make_int2(row[i] | ((c & 63) << 17), __float_as_int(w[i]));
    }
}

// Pass D: one block per bucket (64 nodes). Fine counting sort by c6,
// per-node weighted degree (fixed-point LDS atomics) -> perm {row,wbits},
// offs, dinv. All atomics LDS.
__global__ __launch_bounds__(256)
void fineD_kernel(const int2* __restrict__ semi, const unsigned int* __restrict__ scanned,
                  int* __restrict__ offs, float* __restrict__ dinv,
                  int2* __restrict__ perm, int E, int N, int NB) {
    __shared__ unsigned int cnt[64], cur[64], wsum[64];
    __shared__ int nodeOffs[64];
    int b = blockIdx.x, tid = threadIdx.x;
    int s = (int)scanned[(size_t)b * TB];
    int e = (b + 1 < NB) ? (int)scanned[(size_t)(b + 1) * TB] : E;
    if (tid < 64) { cnt[tid] = 0u; wsum[tid] = 0u; }
    __syncthreads();
    for (int i = s + tid; i < e; i += 256) {
        int2 v = semi[i];
        int c6 = (v.x >> 17) & 63;
        atomicAdd(&cnt[c6], 1u);
        atomicAdd(&wsum[c6], (unsigned int)llrintf(__int_as_float(v.y) * FXSCALE));
    }
    __syncthreads();
    if (tid < 64) {
        int v = (int)cnt[tid];
        int incl = v;
#pragma unroll
        for (int off = 1; off < 64; off <<= 1) {
            int u = __shfl_up(incl, off, 64);
            if (tid >= off) incl += u;
        }
        nodeOffs[tid] = incl - v;          // exclusive within bucket
        cur[tid] = (unsigned int)(incl - v);
    }
    __syncthreads();
    for (int i = s + tid; i < e; i += 256) {
        int2 v = semi[i];
        int c6 = (v.x >> 17) & 63;
        unsigned int r = atomicAdd(&cur[c6], 1u);
        perm[s + (int)r] = make_int2(v.x & 0x1FFFF, v.y);   // {row, wbits}
    }
    if (tid < 64) {
        int node = (b << BKT_SHIFT) + tid;
        if (node < N) {
            offs[node] = s + nodeOffs[tid];
            float deg = (float)wsum[tid] * (1.0f / FXSCALE);
            dinv[node] = rsqrtf(deg + 1.0f);
        }
    }
    if (b == NB - 1 && tid == 0) offs[N] = E;
}

// Pass E: perm.y = dinv[row] * w * dinv[col]  (thread per destination node)
__global__ void normE_kernel(const int* __restrict__ offs, const float* __restrict__ dinv,
                             int2* __restrict__ perm, int N) {
    int n = blockIdx.x * blockDim.x + threadIdx.x;
    if (n >= N) return;
    int s = offs[n], e = offs[n + 1];
    float dc = dinv[n];
    for (int j = s; j < e; ++j) {
        int2 p = perm[j];
        float nm = dinv[p.x] * __int_as_float(p.y) * dc;
        perm[j] = make_int2(p.x, __float_as_int(nm));
    }
}

// Fused conv (conv1/conv2): phase1 = R11 gather into LDS agg (rows padded to
// K+4 floats vs phase-2 bank conflicts); sync; phase2 = gemm from LDS, relu,
// bf16 out. Removes the bufA global round-trip entirely.
template<int K, int FOUT, int NPB, int BLK>
__global__ __launch_bounds__(BLK)
void fused_conv_kernel(const int* __restrict__ offs, const int2* __restrict__ perm,
                       const ushort* __restrict__ H, const float* __restrict__ dinv,
                       const float* __restrict__ W, const float* __restrict__ bias,
                       ushort* __restrict__ out, int N) {
    constexpr int TPN = K / 4;
    constexpr int TPQ = FOUT / 4;
    constexpr int NPT = 4;
    constexpr int KP = K + 4;              // padded agg row (floats)
    static_assert((NPB * TPN) % BLK == 0, "phase1 tiling");
    static_assert((NPB / NPT) * TPQ == BLK, "phase2 tiling");
    __shared__ float wsm[K * FOUT];
    __shared__ float aggs[NPB * KP];
    for (int i = threadIdx.x; i < K * FOUT; i += BLK) wsm[i] = W[i];

    // ---- phase 1: gather into LDS ----
#pragma unroll
    for (int p0 = 0; p0 < NPB * TPN; p0 += BLK) {
        int p = p0 + threadIdx.x;
        int nl = p / TPN, q = p % TPN;
        int node = blockIdx.x * NPB + nl;
        float4 a0 = make_float4(0.f, 0.f, 0.f, 0.f);
        float4 a1 = make_float4(0.f, 0.f, 0.f, 0.f);
        if (node < N) {
            int s = offs[node], e = offs[node + 1];
            int j = s;
            for (; j + 4 <= e; j += 4) {
                int2 p0e = perm[j + 0], p1e = perm[j + 1];
                int2 p2e = perm[j + 2], p3e = perm[j + 3];
                ushort4 u0 = *(const ushort4*)(H + (long)p0e.x * K + q * 4);
                ushort4 u1 = *(const ushort4*)(H + (long)p1e.x * K + q * 4);
                ushort4 u2 = *(const ushort4*)(H + (long)p2e.x * K + q * 4);
                ushort4 u3 = *(const ushort4*)(H + (long)p3e.x * K + q * 4);
                ACC4(a0, u0, __int_as_float(p0e.y));
                ACC4(a1, u1, __int_as_float(p1e.y));
                ACC4(a0, u2, __int_as_float(p2e.y));
                ACC4(a1, u3, __int_as_float(p3e.y));
            }
            for (; j < e; ++j) {
                int2 pe = perm[j];
                ushort4 u = *(const ushort4*)(H + (long)pe.x * K + q * 4);
                ACC4(a0, u, __int_as_float(pe.y));
            }
            float di = dinv[node], d2 = di * di;
            ushort4 su = *(const ushort4*)(H + (long)node * K + q * 4);
            ACC4(a0, su, d2);
        }
        a0.x += a1.x; a0.y += a1.y; a0.z += a1.z; a0.w += a1.w;
        *(float4*)&aggs[nl * KP + q * 4] = a0;
    }
    __syncthreads();

    // ---- phase 2: gemm from LDS ----
    int q = threadIdx.x % TPQ, pg = threadIdx.x / TPQ;
    long nbase = (long)blockIdx.x * NPB + (long)pg * NPT;
    float4 acc[NPT];
#pragma unroll
    for (int t = 0; t < NPT; ++t) acc[t] = make_float4(0.f, 0.f, 0.f, 0.f);
    const float* wq = wsm + q * 4;
#pragma unroll 4
    for (int i = 0; i < K / 4; ++i) {
        float4 xv[NPT];
#pragma unroll
        for (int t = 0; t < NPT; ++t)
            xv[t] = *(const float4*)&aggs[(pg * NPT + t) * KP + i * 4];
#pragma unroll
        for (int j = 0; j < 4; ++j) {
            float4 wv = *(const float4*)(wq + (i * 4 + j) * FOUT);
#pragma unroll
            for (int t = 0; t < NPT; ++t) {
                float v = ((const float*)&xv[t])[j];
                acc[t].x += v * wv.x; acc[t].y += v * wv.y;
                acc[t].z += v * wv.z; acc[t].w += v * wv.w;
            }
        }
    }
    float4 bv = *(const float4*)(bias + q * 4);
#pragma unroll
    for (int t = 0; t < NPT; ++t) {
        long n = nbase + t;
        if (n < N) {
            float ox = fmaxf(acc[t].x + bv.x, 0.f);
            float oy = fmaxf(acc[t].y + bv.y, 0.f);
            float oz = fmaxf(acc[t].z + bv.z, 0.f);
            float ow = fmaxf(acc[t].w + bv.w, 0.f);
            *(ushort4*)(out + n * FOUT + q * 4) =
                make_ushort4(f2bf(ox), f2bf(oy), f2bf(oz), f2bf(ow));
        }
    }
}

// Fused conv3 + pool (R17 body, small-block variant): phase1 = gather NPB
// nodes x 80 feats into LDS; phase2 = 80->128 gemm with W3 from GLOBAL
// (coalesced, L1/L2-hot) + relu + hierarchical max-pool.
// NPB=32, BLK=128: LDS ~12KB -> ~13 independent blocks/CU whose barriers
// drift -> CU-level mix of phase-1 (memory) and phase-2 (FMA) blocks.
template<int K, int FOUT, int NPB, int BLK>
__global__ __launch_bounds__(BLK)
void fused_conv3_pool_kernel(const int* __restrict__ offs, const int2* __restrict__ perm,
                             const ushort* __restrict__ H, const float* __restrict__ dinv,
                             const float* __restrict__ W, const float* __restrict__ bias,
                             const int* __restrict__ batch,
                             unsigned int* __restrict__ g, int N) {
    constexpr int TPN = K / 4;             // 20
    constexpr int TPQ = FOUT / 4;          // 32
    constexpr int NPT = NPB / (BLK / TPQ); // 32 / 4 = 8
    constexpr int KP = K + 4;              // padded agg row (floats)
    static_assert((NPB * TPN) % BLK == 0, "phase1 tiling");
    static_assert((NPB / NPT) * TPQ == BLK, "phase2 tiling");
    __shared__ float aggs[NPB * KP];
    __shared__ unsigned int gma[2 * FOUT];
    __shared__ int gfirst;
    if (threadIdx.x == 0) gfirst = batch[min((int)(blockIdx.x * NPB), N - 1)];
    for (int i = threadIdx.x; i < 2 * FOUT; i += BLK) gma[i] = 0u;

    // ---- phase 1: gather into LDS ----
#pragma unroll
    for (int p0 = 0; p0 < NPB * TPN; p0 += BLK) {
        int p = p0 + threadIdx.x;
        int nl = p / TPN, q = p % TPN;
        int node = blockIdx.x * NPB + nl;
        float4 a0 = make_float4(0.f, 0.f, 0.f, 0.f);
        float4 a1 = make_float4(0.f, 0.f, 0.f, 0.f);
        if (node < N) {
            int s = offs[node], e = offs[node + 1];
            int j = s;
            for (; j + 4 <= e; j += 4) {
                int2 p0e = perm[j + 0], p1e = perm[j + 1];
                int2 p2e = perm[j + 2], p3e = perm[j + 3];
                ushort4 u0 = *(const ushort4*)(H + (long)p0e.x * K + q * 4);
                ushort4 u1 = *(const ushort4*)(H + (long)p1e.x * K + q * 4);
                ushort4 u2 = *(const ushort4*)(H + (long)p2e.x * K + q * 4);
                ushort4 u3 = *(const ushort4*)(H + (long)p3e.x * K + q * 4);
                ACC4(a0, u0, __int_as_float(p0e.y));
                ACC4(a1, u1, __int_as_float(p1e.y));
                ACC4(a0, u2, __int_as_float(p2e.y));
                ACC4(a1, u3, __int_as_float(p3e.y));
            }
            for (; j < e; ++j) {
                int2 pe = perm[j];
                ushort4 u = *(const ushort4*)(H + (long)pe.x * K + q * 4);
                ACC4(a0, u, __int_as_float(pe.y));
            }
            float di = dinv[node], d2 = di * di;
            ushort4 su = *(const ushort4*)(H + (long)node * K + q * 4);
            ACC4(a0, su, d2);
        }
        a0.x += a1.x; a0.y += a1.y; a0.z += a1.z; a0.w += a1.w;
        *(float4*)&aggs[nl * KP + q * 4] = a0;
    }
    __syncthreads();

    // ---- phase 2: gemm (W from global) + pool ----
    int q = threadIdx.x % TPQ, pg = threadIdx.x / TPQ;
    long nbase = (long)blockIdx.x * NPB + (long)pg * NPT;
    float4 acc[NPT];
#pragma unroll
    for (int t = 0; t < NPT; ++t) acc[t] = make_float4(0.f, 0.f, 0.f, 0.f);
    const float* wq = W + q * 4;
#pragma unroll 4
    for (int i = 0; i < K / 4; ++i) {
        float4 xv[NPT];
#pragma unroll
        for (int t = 0; t < NPT; ++t)
            xv[t] = *(const float4*)&aggs[(pg * NPT + t) * KP + i * 4];
#pragma unroll
        for (int j = 0; j < 4; ++j) {
            float4 wv = *(const float4*)(wq + (i * 4 + j) * FOUT);
#pragma unroll
            for (int t = 0; t < NPT; ++t) {
                float v = ((const float*)&xv[t])[j];
                acc[t].x += v * wv.x; acc[t].y += v * wv.y;
                acc[t].z += v * wv.z; acc[t].w += v * wv.w;
            }
        }
    }
    float4 bv = *(const float4*)(bias + q * 4);
#pragma unroll
    for (int t = 0; t < NPT; ++t) {
        long n = nbase + t;
        if (n < N) {
            unsigned int bx = __float_as_uint(fmaxf(acc[t].x + bv.x, 0.f));
            unsigned int by = __float_as_uint(fmaxf(acc[t].y + bv.y, 0.f));
            unsigned int bz = __float_as_uint(fmaxf(acc[t].z + bv.z, 0.f));
            unsigned int bw = __float_as_uint(fmaxf(acc[t].w + bv.w, 0.f));
            int rel = batch[n] - gfirst;
            if (rel < 2) {
                unsigned int* d = gma + rel * FOUT + q * 4;
                atomicMax(d + 0, bx); atomicMax(d + 1, by);
                atomicMax(d + 2, bz); atomicMax(d + 3, bw);
            } else {
                unsigned int* d = g + (long)batch[n] * FOUT + q * 4;
                atomicMax(d + 0, bx); atomicMax(d + 1, by);
                atomicMax(d + 2, bz); atomicMax(d + 3, bw);
            }
        }
    }
    __syncthreads();
    for (int i = threadIdx.x; i < 2 * FOUT; i += BLK) {
        unsigned int v = gma[i];
        if (v) atomicMax(&g[(long)(gfirst + i / FOUT) * FOUT + (i % FOUT)], v);
    }
}

// one block per graph: relu(g@Wfc1+bfc1) @ Wfc2 + bfc2 -> softmax
__global__ void fc_kernel(const float* __restrict__ g, const float* __restrict__ Wfc1,
                          const float* __restrict__ bfc1, const float* __restrict__ Wfc2,
                          const float* __restrict__ bfc2, float* __restrict__ out) {
    __shared__ float gs[128];
    __shared__ float red0[256], red1[256];
    int b = blockIdx.x, tid = threadIdx.x;
    if (tid < 128) gs[tid] = g[b * 128 + tid];
    __syncthreads();
    float h0 = bfc1[tid], h1 = bfc1[tid + 256];
    for (int k = 0; k < 128; ++k) {
        float gv = gs[k];
        h0 += gv * Wfc1[k * 512 + tid];
        h1 += gv * Wfc1[k * 512 + tid + 256];
    }
    h0 = fmaxf(h0, 0.f); h1 = fmaxf(h1, 0.f);
    red0[tid] = h0 * Wfc2[tid * 2 + 0] + h1 * Wfc2[(tid + 256) * 2 + 0];
    red1[tid] = h0 * Wfc2[tid * 2 + 1] + h1 * Wfc2[(tid + 256) * 2 + 1];
    __syncthreads();
    for (int s = 128; s > 0; s >>= 1) {
        if (tid < s) { red0[tid] += red0[tid + s]; red1[tid] += red1[tid + s]; }
        __syncthreads();
    }
    if (tid == 0) {
        float L0 = red0[0] + bfc2[0], L1 = red1[0] + bfc2[1];
        float m = fmaxf(L0, L1);
        float e0 = expf(L0 - m), e1 = expf(L1 - m);
        float inv = 1.f / (e0 + e1);
        out[b * 2 + 0] = e0 * inv;
        out[b * 2 + 1] = e1 * inv;
    }
}

extern "C" void kernel_launch(void* const* d_in, const int* in_sizes, int n_in,
                              void* d_out, int out_size, void* d_ws, size_t ws_size,
                              hipStream_t stream) {
    const float* x     = (const float*)d_in[0];
    const int*   ei    = (const int*)d_in[1];
    const float* ew    = (const float*)d_in[2];
    const int*   batch = (const int*)d_in[3];
    const float* W1    = (const float*)d_in[4];
    const float* b1    = (const float*)d_in[5];
    const float* W2    = (const float*)d_in[6];
    const float* b2    = (const float*)d_in[7];
    const float* W3    = (const float*)d_in[8];
    const float* b3    = (const float*)d_in[9];
    const float* Wfc1  = (const float*)d_in[10];
    const float* bfc1  = (const float*)d_in[11];
    const float* Wfc2  = (const float*)d_in[12];
    const float* bfc2  = (const float*)d_in[13];

    const int N = in_sizes[3];      // 100000
    const int E = in_sizes[2];      // 1600000
    const int* row = ei;
    const int* col = ei + E;

    char* ws = (char*)d_ws;
    float* dinv   = (float*)ws;              ws += align256((size_t)N * 4);
    int*   offs   = (int*)ws;                ws += align256((size_t)(N + 1) * 4);
    int*   bsums  = (int*)ws;                ws += align256((size_t)1024 * 4);
    int2*  perm   = (int2*)ws;               ws += align256((size_t)E * 8);
    float* bufA   = (float*)ws;              ws += align256((size_t)N * 128 * 4);  // build transients
    ushort* bufH1 = (ushort*)ws;             ws += align256((size_t)N * 40 * 2);   // H1 bf16
    ushort* bufH2 = (ushort*)ws;             ws += align256((size_t)N * 80 * 2);   // H2 bf16
    ushort* xbf   = (ushort*)ws;             ws += align256((size_t)N * 40 * 2);   // x bf16
    float* g      = (float*)ws;              ws += align256((size_t)512 * 128 * 4);

    const int NB   = cdiv(N, 64);            // 1563 buckets (<= MAXNB)
    const int TOT  = NB * TB;                // (bucket, tile) cells = 400128
    const int chunkE = cdiv(E, TB);          // edges per tile = 6250
    const int nScanH = cdiv(TOT, SCHUNK);    // 391 (<= 1024)

    // transients aliased into bufA (51.2MB; all dead before convs):
    // semi int2 (12.8MB) | gHist u32[TOT] (1.6MB) | scanned u32[TOT] (1.6MB)
    int2* semi = (int2*)bufA;
    unsigned int* gHist =
        (unsigned int*)((char*)bufA + align256((size_t)E * 8));
    unsigned int* scanned =
        (unsigned int*)((char*)gHist + align256((size_t)TOT * 4));

    const int B = 256;

    // --- atomic-free CSR build ---
    histA_kernel<<<TB, 512, 0, stream>>>(col, gHist, E, NB, chunkE,
                                         x, xbf, (long)N * 10);
    scanAH_kernel<<<nScanH, B, 0, stream>>>(gHist, bsums, TOT, NB);
    scanB_kernel<<<1, 1024, 0, stream>>>(bsums, offs, nScanH, N);
    scanCH_kernel<<<nScanH, B, 0, stream>>>(gHist, bsums, scanned, TOT, NB);
    scatterC_kernel<<<TB, 512, 0, stream>>>(row, col, ew, scanned, semi, E, NB, chunkE);
    fineD_kernel<<<NB, 256, 0, stream>>>(semi, scanned, offs, dinv, perm, E, N, NB);
    normE_kernel<<<cdiv(N, B), B, 0, stream>>>(offs, dinv, perm, N);

    // --- conv1 fused: H1 = relu((A*x)@W1 + b1) -> bufH1 (bf16) ---
    fused_conv_kernel<40, 40, 128, 320><<<cdiv(N, 128), 320, 0, stream>>>(
        offs, perm, xbf, dinv, W1, b1, bufH1, N);

    // --- conv2 fused: H2 = relu((A*H1)@W2 + b2) -> bufH2 (bf16) ---
    fused_conv_kernel<40, 80, 64, 320><<<cdiv(N, 64), 320, 0, stream>>>(
        offs, perm, bufH1, dinv, W2, b2, bufH2, N);

    // --- conv3 fused (small blocks): pool(relu((A*H2)@W3 + b3)) -> g ---
    hipMemsetAsync(g, 0, (size_t)512 * 128 * 4, stream);
    fused_conv3_pool_kernel<80, 128, 32, 128><<<cdiv(N, 32), 128, 0, stream>>>(
        offs, perm, bufH2, dinv, W3, b3, batch, (unsigned int*)g, N);

    // --- MLP + softmax ---
    fc_kernel<<<512, 256, 0, stream>>>(g, Wfc1, bfc1, Wfc2, bfc2, (float*)d_out);
}